// Round 2
// baseline (465.874 us; speedup 1.0000x reference)
//
#include <hip/hip_runtime.h>
#include <hip/hip_bf16.h>
#include <stdint.h>

// Problem: B=32, C_IN=128, H=W=64, K=8, C_OUT=128, KS=3, HID=512, pad=1
// Pipeline:
//  1) pool_convert: x fp32 NCHW -> per-(b,h) partial sums + xT bf16 NHWC
//  2) attn_mlp:     reduce partials -> MLP (wave-coalesced) -> softmax + agg_b
//  3) agg_weights:  alphas x kernels_weights -> aggw bf16 [b][tap][co][ci]
//  4) dyn_conv:     implicit-GEMM conv; x via LDS, A-frags DIRECT from global
//                   (3 barriers total instead of 36 - AITER-style vmcnt overlap)

typedef __bf16 v8bf __attribute__((ext_vector_type(8)));
typedef float  v4f  __attribute__((ext_vector_type(4)));

// ---- workspace layout (bytes) ----
#define XT_OFF     0u
#define XT_BYTES   (32u*4096u*128u*2u)        // 33,554,432  x as bf16 NHWC
#define AGGW_OFF   (XT_OFF + XT_BYTES)
#define AGGW_BYTES (32u*9u*128u*128u*2u)      // 9,437,184   [b][tap][co][ci]
// partial pooled sums alias the AGGW region (consumed by attn BEFORE agg runs)
#define PART_OFF   AGGW_OFF                   // 32*64*128 fp32 = 1 MB
#define ALPHA_OFF  (AGGW_OFF + AGGW_BYTES)
#define ALPHA_BYTES (32u*8u*4u)
#define AGGB_OFF   (ALPHA_OFF + ALPHA_BYTES)
#define AGGB_BYTES (32u*128u*4u)

typedef const void __attribute__((address_space(1))) gconst_t;
typedef void       __attribute__((address_space(3))) ldsv_t;

__device__ __forceinline__ void g2l16(const void* g, void* l) {
  // async global->LDS, 16B/lane; LDS dest is wave-uniform base (HW adds lane*16)
  __builtin_amdgcn_global_load_lds((gconst_t*)g, (ldsv_t*)l, 16, 0, 0);
}

// ---------------- Kernel 1: pooling partials + NCHW->NHWC bf16 ---------------
// grid = B*H = 2048 blocks, 256 threads. Each block handles one (b,h) row slab.
__global__ __launch_bounds__(256) void pool_convert_kernel(
    const float* __restrict__ x, float* __restrict__ partial,
    __hip_bfloat16* __restrict__ xT) {
  const int b = blockIdx.x >> 6;
  const int h = blockIdx.x & 63;
  const int tid = threadIdx.x;
  const int wv = tid >> 6, lane = tid & 63;
  // [w][c] transpose buffer; pitch 130 elems (260B) => 2-way bank aliasing (free)
  __shared__ __align__(16) __hip_bfloat16 sT[64 * 130];

  const float* xrow = x + (((size_t)b * 128) << 12) + (h << 6);
  for (int i = 0; i < 32; ++i) {
    int c = wv * 32 + i;                       // each wave: 32 channels
    float v = xrow[((size_t)c << 12) + lane];  // coalesced 256B per wave
    sT[lane * 130 + c] = __float2bfloat16(v);
    float s = v;
    #pragma unroll
    for (int m = 32; m > 0; m >>= 1) s += __shfl_xor(s, m);
    if (lane == 0) partial[((b << 6) + h) * 128 + c] = s;  // unique slot, no atomic
  }
  __syncthreads();
  // write NHWC: position (h,pw) has 256B of ci; 4 threads/position, 64B each
  const int pw = tid >> 2;
  const int piece = tid & 3;
  const uint32_t* s32 = (const uint32_t*)sT;
  uint32_t vals[16];
  #pragma unroll
  for (int j = 0; j < 16; ++j) vals[j] = s32[pw * 65 + piece * 16 + j];
  char* dst = (char*)xT + ((((size_t)b << 6) + h) * 64 + pw) * 256 + piece * 64;
  #pragma unroll
  for (int j = 0; j < 4; ++j)
    ((uint4*)dst)[j] = make_uint4(vals[4*j], vals[4*j+1], vals[4*j+2], vals[4*j+3]);
}

// ---------------- Kernel 2: MLP + prompt scores + softmax + agg_b ------------
// grid = 32 (one block per sample), 256 threads, fp32.
// All dot products are WAVE-COOPERATIVE: lanes stride the reduction axis so
// every global load is coalesced (the previous thread-per-row version gathered
// 64 cache lines per wave instruction).
__global__ __launch_bounds__(256) void attn_mlp_kernel(
    const float* __restrict__ partial, const float* __restrict__ w1,
    const float* __restrict__ b1, const float* __restrict__ w2,
    const float* __restrict__ b2, const float* __restrict__ prompt,
    const float* __restrict__ kbias, float* __restrict__ alphas,
    float* __restrict__ aggb) {
  const int b = blockIdx.x;
  const int tid = threadIdx.x;
  const int wv = tid >> 6, lane = tid & 63;
  __shared__ float sP[128], sH[512], sS[512], sSc[8], sA[8];

  if (tid < 128) {                                  // reduce 64 h-partials
    float acc = 0.0f;
    const float* src = partial + (b << 6) * 128 + tid;
    #pragma unroll 8
    for (int h = 0; h < 64; ++h) acc += src[h * 128];
    sP[tid] = acc * (1.0f / 4096.0f);
  }
  __syncthreads();

  // layer 1: h = relu(pooled @ w1^T + b1); each wave: 128 j's, lanes over i
  #pragma unroll 2
  for (int j = wv; j < 512; j += 4) {
    const float* wr = w1 + j * 128;
    float p = fmaf(wr[lane], sP[lane], wr[lane + 64] * sP[lane + 64]);
    #pragma unroll
    for (int m = 32; m > 0; m >>= 1) p += __shfl_xor(p, m);
    if (lane == 0) sH[j] = fmaxf(p + b1[j], 0.0f);
  }
  __syncthreads();

  // layer 2: s = h @ w2^T + b2
  #pragma unroll 2
  for (int j = wv; j < 512; j += 4) {
    const float* wr = w2 + j * 512;
    float p = 0.0f;
    #pragma unroll
    for (int it = 0; it < 8; ++it)
      p = fmaf(wr[lane + 64 * it], sH[lane + 64 * it], p);
    #pragma unroll
    for (int m = 32; m > 0; m >>= 1) p += __shfl_xor(p, m);
    if (lane == 0) sS[j] = p + b2[j];
  }
  __syncthreads();

  for (int k = wv; k < 8; k += 4) {                 // scores[k] = <s, prompt[k]>
    float p = 0.0f;
    const float* pr = prompt + k * 512;
    #pragma unroll
    for (int it = 0; it < 8; ++it)
      p = fmaf(pr[lane + 64 * it], sS[lane + 64 * it], p);
    #pragma unroll
    for (int m = 32; m > 0; m >>= 1) p += __shfl_xor(p, m);
    if (lane == 0) sSc[k] = p;
  }
  __syncthreads();

  if (tid == 0) {                                   // softmax over 8 kernels
    float mx = sSc[0];
    for (int k = 1; k < 8; ++k) mx = fmaxf(mx, sSc[k]);
    float sum = 0.0f, e[8];
    for (int k = 0; k < 8; ++k) { e[k] = expf(sSc[k] - mx); sum += e[k]; }
    float inv = 1.0f / sum;
    for (int k = 0; k < 8; ++k) sA[k] = e[k] * inv;
  }
  __syncthreads();

  if (tid < 8) alphas[b * 8 + tid] = sA[tid];
  if (tid < 128) {                                  // agg_b = alphas @ kernels_bias
    float acc = 0.0f;
    #pragma unroll
    for (int k = 0; k < 8; ++k) acc = fmaf(sA[k], kbias[k * 128 + tid], acc);
    aggb[b * 128 + tid] = acc;
  }
}

// ---------------- Kernel 3: aggregate conv weights -> bf16 -------------------
// grid = (co=128, bgroup=4), 128 threads. Flat-index reads (coalesced 512B),
// LDS transpose, coalesced bf16 stores. out layout [b][tap][co][ci].
__global__ __launch_bounds__(128) void agg_weights_kernel(
    const float* __restrict__ kw, const float* __restrict__ alphas,
    __hip_bfloat16* __restrict__ aggw) {
  const int co = blockIdx.x;
  const int bg = blockIdx.y;
  const int tid = threadIdx.x;
  __shared__ float sA[64];                          // [bb][k]
  __shared__ float sbuf[1152];
  if (tid < 64) sA[tid] = alphas[bg * 64 + tid];
  __syncthreads();

  float acc[8][9];                                  // [bb][q], f = tid + 128*q
  #pragma unroll
  for (int bb = 0; bb < 8; ++bb)
    #pragma unroll
    for (int q = 0; q < 9; ++q) acc[bb][q] = 0.0f;

  for (int k = 0; k < 8; ++k) {
    const float* src = kw + ((size_t)(k * 128 + co)) * 1152;
    float v[9];
    #pragma unroll
    for (int q = 0; q < 9; ++q) v[q] = src[tid + 128 * q];   // coalesced
    #pragma unroll
    for (int bb = 0; bb < 8; ++bb) {
      float a = sA[bb * 8 + k];
      #pragma unroll
      for (int q = 0; q < 9; ++q) acc[bb][q] = fmaf(a, v[q], acc[bb][q]);
    }
  }

  #pragma unroll 1
  for (int bb = 0; bb < 8; ++bb) {
    __syncthreads();
    #pragma unroll
    for (int q = 0; q < 9; ++q) sbuf[tid + 128 * q] = acc[bb][q];
    __syncthreads();
    const int b = bg * 8 + bb;
    // sbuf[f] with f = ci*9 + t; lanes read stride 9 (9 coprime 32: conflict-free)
    #pragma unroll
    for (int t = 0; t < 9; ++t)
      aggw[(((size_t)(b * 9 + t) * 128 + co) << 7) + tid] =
          __float2bfloat16(sbuf[tid * 9 + t]);     // 256B contiguous store
  }
}

// ---------------- Kernel 4: per-sample conv as implicit GEMM -----------------
// Block tile: M=128 (co) x N=128 (2 rows x 64 cols). 4 waves, 64x64 each.
// x staged per ci-half (64 ci) in LDS NHWC with 16B XOR swizzle.
// A fragments loaded DIRECTLY global->VGPR (16B/lane, L1/L2-served, 32 blocks
// share each sample's 294KB) -> no A-LDS, no per-chunk barriers (3 total).
#define XTILE_B 33792   // 264 positions * 128B (64 ci bf16)

__global__ __launch_bounds__(256, 4) void dyn_conv_kernel(
    const __hip_bfloat16* __restrict__ xT, const __hip_bfloat16* __restrict__ aggw,
    const float* __restrict__ aggb, float* __restrict__ out) {
  const int tile = blockIdx.x;   // 0..31 -> rows [2*tile, 2*tile+1]
  const int b    = blockIdx.y;   // sample
  const int tid  = threadIdx.x;
  const int wv = tid >> 6, lane = tid & 63;
  const int wm = wv >> 1, wn = wv & 1;
  const int lm = lane & 15, quad = lane >> 4;
  const int r0 = tile * 2;

  __shared__ __align__(16) char smem[XTILE_B + 512];
  char* xb = smem;
  float* sBias = (float*)(smem + XTILE_B);

  if (tid < 128) sBias[tid] = aggb[b * 128 + tid];

  // zero-fill halo slots that staging never writes (pad cols / out-of-range rows)
  for (int pos = tid; pos < 264; pos += 256) {
    int tr = pos / 66, tc = pos - tr * 66;
    int h = r0 - 1 + tr, w = tc - 1;
    if ((unsigned)h >= 64u || (unsigned)w >= 64u) {
      int4* d = (int4*)(xb + pos * 128);
      #pragma unroll
      for (int i = 0; i < 8; ++i) d[i] = make_int4(0, 0, 0, 0);
    }
  }

  const char* xTb = (const char*)xT + ((size_t)b << 20);     // b*4096*256
  const char* awb = (const char*)aggw + (size_t)b * 294912;  // b*9*128*256

  auto stageX = [&](int half) {
    for (int i = wv; i < 33; i += 4) {          // 33 issues of 64x16B = 1KB
      int P = (i << 6) + lane;
      int pos = P >> 3, slot = P & 7;
      int tr = pos / 66, tc = pos - tr * 66;
      int h = r0 - 1 + tr, w = tc - 1;
      char* dst = xb + (i << 10);               // wave-uniform LDS base
      if ((unsigned)h < 64u && (unsigned)w < 64u) {
        int p = slot ^ (pos & 7);               // swizzled source piece
        const char* src = xTb + (((h << 6) + w) << 8) + (half << 7) + (p << 4);
        g2l16(src, dst);
      }
    }
  };

  // per-lane A fragment base offsets: co = wm*64 + mi*16 + lm, k-piece = quad
  int aoffB[4];
  #pragma unroll
  for (int mi = 0; mi < 4; ++mi)
    aoffB[mi] = ((wm * 64 + mi * 16 + lm) << 8) + (quad << 4);

  int posb[4];
  #pragma unroll
  for (int ni = 0; ni < 4; ++ni) {
    int n = wn * 64 + ni * 16 + lm;
    posb[ni] = (n >> 6) * 66 + (n & 63);
  }

  v4f acc[4][4];
  #pragma unroll
  for (int mi = 0; mi < 4; ++mi)
    #pragma unroll
    for (int ni = 0; ni < 4; ++ni) acc[mi][ni] = v4f{0.f, 0.f, 0.f, 0.f};

  auto loadA = [&](int c, v8bf* dst) {
    int tap = (c % 18) >> 1;
    int cic = ((c / 18) << 1) | (c & 1);        // ci chunk 0..3
    const char* base = awb + (tap << 15) + (cic << 6);
    #pragma unroll
    for (int mi = 0; mi < 4; ++mi)
      dst[mi] = *(const v8bf*)(base + aoffB[mi]);
  };

  auto computeChunk = [&](int c, const v8bf* af) {
    int tap = (c % 18) >> 1, sub = c & 1;
    int th = tap / 3, tw = tap - th * 3;
    const int piece = (sub << 2) | quad;        // ci piece within half
    #pragma unroll
    for (int ni = 0; ni < 4; ++ni) {
      int pos = posb[ni] + th * 66 + tw;
      int pp = (piece ^ (pos & 7)) << 4;
      v8bf bfr = *(const v8bf*)(xb + (pos << 7) + pp);
      #pragma unroll
      for (int mi = 0; mi < 4; ++mi)
        acc[mi][ni] = __builtin_amdgcn_mfma_f32_16x16x32_bf16(
            af[mi], bfr, acc[mi][ni], 0, 0, 0);
    }
  };

  // ---- main loop: 36 K-chunks (9 taps x 4 ci-chunks), x half-swap at c=18 ----
  v8bf afA[4], afB[4];
  stageX(0);
  loadA(0, afA);
  __syncthreads();                               // drains stageX(0) + afA
  #pragma unroll
  for (int c = 0; c < 36; ++c) {
    if (c == 18) {
      __syncthreads();                           // all waves done reading half 0
      stageX(1);
      __syncthreads();                           // half 1 resident
    }
    v8bf* cur = (c & 1) ? afB : afA;
    v8bf* nxt = (c & 1) ? afA : afB;
    if (c < 35) loadA(c + 1, nxt);               // overlap with MFMA (vmcnt)
    computeChunk(c, cur);
  }

  // ---- epilogue: C/D layout col=lane&15, row=quad*4+reg ----
  #pragma unroll
  for (int mi = 0; mi < 4; ++mi) {
    #pragma unroll
    for (int r = 0; r < 4; ++r) {
      int co = wm * 64 + mi * 16 + quad * 4 + r;
      float bias = sBias[co];
      #pragma unroll
      for (int ni = 0; ni < 4; ++ni) {
        int n = wn * 64 + ni * 16 + lm;
        out[(((size_t)(b * 128 + co)) << 12) + tile * 128 + n] =
            acc[mi][ni][r] + bias;
      }
    }
  }
}

// ---------------------------------- launch -----------------------------------
extern "C" void kernel_launch(void* const* d_in, const int* in_sizes, int n_in,
                              void* d_out, int out_size, void* d_ws, size_t ws_size,
                              hipStream_t stream) {
  const float* x      = (const float*)d_in[0];
  const float* prompt = (const float*)d_in[1];
  const float* w1     = (const float*)d_in[2];
  const float* b1     = (const float*)d_in[3];
  const float* w2     = (const float*)d_in[4];
  const float* b2     = (const float*)d_in[5];
  const float* kw     = (const float*)d_in[6];
  const float* kb     = (const float*)d_in[7];
  float* out = (float*)d_out;
  char* ws = (char*)d_ws;

  __hip_bfloat16* xT   = (__hip_bfloat16*)(ws + XT_OFF);
  __hip_bfloat16* aggw = (__hip_bfloat16*)(ws + AGGW_OFF);
  float* part   = (float*)(ws + PART_OFF);   // aliases AGGW region (safe: serial)
  float* alphas = (float*)(ws + ALPHA_OFF);
  float* aggb   = (float*)(ws + AGGB_OFF);

  pool_convert_kernel<<<2048, 256, 0, stream>>>(x, part, xT);
  attn_mlp_kernel<<<32, 256, 0, stream>>>(part, w1, b1, w2, b2, prompt, kb,
                                          alphas, aggb);
  agg_weights_kernel<<<dim3(128, 4), 128, 0, stream>>>(kw, alphas, aggw);
  dyn_conv_kernel<<<dim3(32, 32), 256, 0, stream>>>(xT, aggw, aggb, out);
}

// Round 3
// 228.659 us; speedup vs baseline: 2.0374x; 2.0374x over previous
//
#include <hip/hip_runtime.h>
#include <hip/hip_bf16.h>
#include <stdint.h>

// Problem: B=32, C_IN=128, H=W=64, K=8, C_OUT=128, KS=3, HID=512, pad=1
// Pipeline:
//  1) pool_convert: x fp32 NCHW -> per-(b,h) partial sums + xT bf16 NHWC
//  2) pool_reduce:  partials -> pooled means
//  3) attn_l1:      h = relu(pooled @ w1^T + b1)        (LDS-staged, 64 blocks)
//  4) attn_l2s:     partial scores via w2 + prompt      (LDS-staged, 128 blocks)
//  5) softmax_aggb: reduce partial scores -> alphas, agg_b
//  6) agg_weights:  alphas x kernels_weights -> aggw bf16 [b][tap][co][ci]
//  7) dyn_conv:     implicit-GEMM conv (Round-1 proven version: LDS A dbuf)

typedef __bf16 v8bf __attribute__((ext_vector_type(8)));
typedef float  v4f  __attribute__((ext_vector_type(4)));

// ---- workspace layout (bytes) ----
#define XT_OFF     0u
#define XT_BYTES   (32u*4096u*128u*2u)        // 33,554,432  x as bf16 NHWC
#define AGGW_OFF   (XT_OFF + XT_BYTES)
#define AGGW_BYTES (32u*9u*128u*128u*2u)      // 9,437,184   [b][tap][co][ci]
// scratch below ALIASES the AGGW region: all consumed before agg_weights writes
#define PART_OFF   (AGGW_OFF)                 // 32*64*128 fp32 = 1 MB
#define POOLED_OFF (AGGW_OFF + 0x100000u)     // 32*128 fp32 = 16 KB
#define H_OFF      (AGGW_OFF + 0x110000u)     // 32*512 fp32 = 64 KB
#define PSCORE_OFF (AGGW_OFF + 0x120000u)     // 64*32*8 fp32 = 64 KB
#define ALPHA_OFF  (AGGW_OFF + AGGW_BYTES)
#define ALPHA_BYTES (32u*8u*4u)
#define AGGB_OFF   (ALPHA_OFF + ALPHA_BYTES)
#define AGGB_BYTES (32u*128u*4u)

typedef const void __attribute__((address_space(1))) gconst_t;
typedef void       __attribute__((address_space(3))) ldsv_t;

__device__ __forceinline__ void g2l16(const void* g, void* l) {
  // async global->LDS, 16B/lane; LDS dest is wave-uniform base (HW adds lane*16)
  __builtin_amdgcn_global_load_lds((gconst_t*)g, (ldsv_t*)l, 16, 0, 0);
}

// ---------------- Kernel 1: pooling partials + NCHW->NHWC bf16 ---------------
// grid = B*H = 2048 blocks, 256 threads. Each block handles one (b,h) row slab.
__global__ __launch_bounds__(256) void pool_convert_kernel(
    const float* __restrict__ x, float* __restrict__ partial,
    __hip_bfloat16* __restrict__ xT) {
  const int b = blockIdx.x >> 6;
  const int h = blockIdx.x & 63;
  const int tid = threadIdx.x;
  const int wv = tid >> 6, lane = tid & 63;
  // [w][c] transpose buffer; pitch 130 elems (260B) => 2-way bank aliasing (free)
  __shared__ __align__(16) __hip_bfloat16 sT[64 * 130];

  const float* xrow = x + (((size_t)b * 128) << 12) + (h << 6);
  for (int i = 0; i < 32; ++i) {
    int c = wv * 32 + i;                       // each wave: 32 channels
    float v = xrow[((size_t)c << 12) + lane];  // coalesced 256B per wave
    sT[lane * 130 + c] = __float2bfloat16(v);
    float s = v;
    #pragma unroll
    for (int m = 32; m > 0; m >>= 1) s += __shfl_xor(s, m);
    if (lane == 0) partial[((b << 6) + h) * 128 + c] = s;  // unique slot
  }
  __syncthreads();
  // write NHWC: position (h,pw) has 256B of ci; 4 threads/position, 64B each
  const int pw = tid >> 2;
  const int piece = tid & 3;
  const uint32_t* s32 = (const uint32_t*)sT;
  uint32_t vals[16];
  #pragma unroll
  for (int j = 0; j < 16; ++j) vals[j] = s32[pw * 65 + piece * 16 + j];
  char* dst = (char*)xT + ((((size_t)b << 6) + h) * 64 + pw) * 256 + piece * 64;
  #pragma unroll
  for (int j = 0; j < 4; ++j)
    ((uint4*)dst)[j] = make_uint4(vals[4*j], vals[4*j+1], vals[4*j+2], vals[4*j+3]);
}

// ---------------- Kernel 2: reduce pooling partials --------------------------
// grid = 32 (b), 128 threads (c). c is fastest dim of partial -> coalesced.
__global__ __launch_bounds__(128) void pool_reduce_kernel(
    const float* __restrict__ partial, float* __restrict__ pooled) {
  const int b = blockIdx.x, c = threadIdx.x;
  float acc = 0.0f;
  const float* src = partial + ((size_t)b << 6) * 128 + c;
  #pragma unroll 8
  for (int h = 0; h < 64; ++h) acc += src[h * 128];
  pooled[b * 128 + c] = acc * (1.0f / 4096.0f);
}

// ---------------- Kernel 3: layer 1, h = relu(pooled @ w1^T + b1) ------------
// grid = 64 blocks (8 j's each), 256 threads = one (b, j) pair per thread.
// w1 tile + pooled staged in LDS with +4 float pad (conflict-free / 2-way).
__global__ __launch_bounds__(256) void attn_l1_kernel(
    const float* __restrict__ pooled, const float* __restrict__ w1,
    const float* __restrict__ b1, float* __restrict__ hbuf) {
  const int jt = blockIdx.x * 8;
  const int tid = threadIdx.x;
  __shared__ float sW[8 * 132];
  __shared__ float sPool[32 * 132];

  {  // stage w1 rows jt..jt+7 (1024 floats) as float4
    int r = tid >> 5, c4 = (tid & 31) * 4;
    *(float4*)&sW[r * 132 + c4] = *(const float4*)&w1[(jt + r) * 128 + c4];
  }
  #pragma unroll
  for (int q = 0; q < 4; ++q) {  // stage pooled (4096 floats) as float4
    int idx = q * 256 + tid;
    int bb = idx >> 5, c4 = (idx & 31) * 4;
    *(float4*)&sPool[bb * 132 + c4] = *(const float4*)&pooled[bb * 128 + c4];
  }
  __syncthreads();

  const int b = tid >> 3, jr = tid & 7;
  float acc = 0.0f;
  #pragma unroll
  for (int i4 = 0; i4 < 32; ++i4) {
    float4 pv = *(const float4*)&sPool[b * 132 + i4 * 4];
    float4 wv = *(const float4*)&sW[jr * 132 + i4 * 4];
    acc += pv.x * wv.x + pv.y * wv.y + pv.z * wv.z + pv.w * wv.w;
  }
  hbuf[b * 512 + jt + jr] = fmaxf(acc + b1[jt + jr], 0.0f);
}

// ---------------- Kernel 4: layer 2 + prompt partial scores ------------------
// grid = 128 blocks: (jtile 0..63 of 8 j's) x (bgroup 0..1 of 16 b's).
// 256 threads: 128 (b,j) pairs x 2 i-halves. s is never materialized; each
// block emits partial scores [jtile][b][k] (reduced by kernel 5).
__global__ __launch_bounds__(256) void attn_l2s_kernel(
    const float* __restrict__ hbuf, const float* __restrict__ w2,
    const float* __restrict__ b2, const float* __restrict__ prompt,
    float* __restrict__ pscore) {
  const int jtile = blockIdx.x >> 1;
  const int bg = blockIdx.x & 1;
  const int jt = jtile * 8;
  const int tid = threadIdx.x;
  __shared__ float sW2[8 * 516];    // 16.5 KB
  __shared__ float sH[16 * 516];    // 33 KB
  __shared__ float sSc[16 * 9];
  __shared__ float sPr[64];

  #pragma unroll
  for (int q = 0; q < 4; ++q) {  // w2 tile: 8x512 floats
    int idx = q * 256 + tid;
    int r = idx >> 7, c4 = (idx & 127) * 4;
    *(float4*)&sW2[r * 516 + c4] = *(const float4*)&w2[(jt + r) * 512 + c4];
  }
  #pragma unroll
  for (int q = 0; q < 8; ++q) {  // h tile: 16x512 floats
    int idx = q * 256 + tid;
    int r = idx >> 7, c4 = (idx & 127) * 4;
    *(float4*)&sH[r * 516 + c4] =
        *(const float4*)&hbuf[(bg * 16 + r) * 512 + c4];
  }
  if (tid < 64) sPr[tid] = prompt[(tid >> 3) * 512 + jt + (tid & 7)];
  __syncthreads();

  const int pair = tid >> 1, half = tid & 1;
  const int bl = pair >> 3, jr = pair & 7;
  float acc = 0.0f;
  #pragma unroll
  for (int i4 = 0; i4 < 64; ++i4) {
    int idx = (half * 64 + i4) * 4;
    float4 hv = *(const float4*)&sH[bl * 516 + idx];
    float4 wv = *(const float4*)&sW2[jr * 516 + idx];
    acc += hv.x * wv.x + hv.y * wv.y + hv.z * wv.z + hv.w * wv.w;
  }
  acc += __shfl_xor(acc, 1);                  // combine the two i-halves
  if (half == 0) sSc[bl * 9 + jr] = acc + b2[jt + jr];
  __syncthreads();

  if (tid < 128) {                            // partial score (b,k) over 8 j's
    int bl = tid >> 3, k = tid & 7;
    float p = 0.0f;
    #pragma unroll
    for (int jj = 0; jj < 8; ++jj) p = fmaf(sSc[bl * 9 + jj], sPr[k * 8 + jj], p);
    pscore[((size_t)(jtile * 32 + bg * 16 + bl)) * 8 + k] = p;  // coalesced
  }
}

// ---------------- Kernel 5: reduce scores + softmax + agg_b ------------------
// grid = 32 (b), 256 threads.
__global__ __launch_bounds__(256) void softmax_aggb_kernel(
    const float* __restrict__ pscore, const float* __restrict__ kbias,
    float* __restrict__ alphas, float* __restrict__ aggb) {
  const int b = blockIdx.x;
  const int tid = threadIdx.x;
  __shared__ float sRed[32 * 8], sSc[8], sA[8];

  {  // each thread folds two of the 64 jtile partials
    int jt2 = tid >> 3, k = tid & 7;
    sRed[jt2 * 8 + k] = pscore[((size_t)(jt2 * 32 + b)) * 8 + k] +
                        pscore[((size_t)((jt2 + 32) * 32 + b)) * 8 + k];
  }
  __syncthreads();
  if (tid < 8) {
    float sc = 0.0f;
    #pragma unroll
    for (int j = 0; j < 32; ++j) sc += sRed[j * 8 + tid];
    sSc[tid] = sc;
  }
  __syncthreads();
  if (tid == 0) {
    float mx = sSc[0];
    for (int k = 1; k < 8; ++k) mx = fmaxf(mx, sSc[k]);
    float sum = 0.0f, e[8];
    for (int k = 0; k < 8; ++k) { e[k] = expf(sSc[k] - mx); sum += e[k]; }
    float inv = 1.0f / sum;
    for (int k = 0; k < 8; ++k) sA[k] = e[k] * inv;
  }
  __syncthreads();
  if (tid < 8) alphas[b * 8 + tid] = sA[tid];
  if (tid < 128) {
    float acc = 0.0f;
    #pragma unroll
    for (int k = 0; k < 8; ++k) acc = fmaf(sA[k], kbias[k * 128 + tid], acc);
    aggb[b * 128 + tid] = acc;
  }
}

// ---------------- Kernel 6: aggregate conv weights -> bf16 -------------------
// grid = (co=128, bgroup=4), 128 threads. Flat-index reads (coalesced 512B),
// LDS transpose, coalesced bf16 stores. out layout [b][tap][co][ci].
__global__ __launch_bounds__(128) void agg_weights_kernel(
    const float* __restrict__ kw, const float* __restrict__ alphas,
    __hip_bfloat16* __restrict__ aggw) {
  const int co = blockIdx.x;
  const int bg = blockIdx.y;
  const int tid = threadIdx.x;
  __shared__ float sA[64];                          // [bb][k]
  __shared__ float sbuf[1152];
  if (tid < 64) sA[tid] = alphas[bg * 64 + tid];
  __syncthreads();

  float acc[8][9];                                  // [bb][q], f = tid + 128*q
  #pragma unroll
  for (int bb = 0; bb < 8; ++bb)
    #pragma unroll
    for (int q = 0; q < 9; ++q) acc[bb][q] = 0.0f;

  for (int k = 0; k < 8; ++k) {
    const float* src = kw + ((size_t)(k * 128 + co)) * 1152;
    float v[9];
    #pragma unroll
    for (int q = 0; q < 9; ++q) v[q] = src[tid + 128 * q];   // coalesced
    #pragma unroll
    for (int bb = 0; bb < 8; ++bb) {
      float a = sA[bb * 8 + k];
      #pragma unroll
      for (int q = 0; q < 9; ++q) acc[bb][q] = fmaf(a, v[q], acc[bb][q]);
    }
  }

  #pragma unroll 1
  for (int bb = 0; bb < 8; ++bb) {
    __syncthreads();
    #pragma unroll
    for (int q = 0; q < 9; ++q) sbuf[tid + 128 * q] = acc[bb][q];
    __syncthreads();
    const int b = bg * 8 + bb;
    // sbuf[f] with f = ci*9 + t; lanes read stride 9 (9 coprime 32: conflict-free)
    #pragma unroll
    for (int t = 0; t < 9; ++t)
      aggw[(((size_t)(b * 9 + t) * 128 + co) << 7) + tid] =
          __float2bfloat16(sbuf[tid * 9 + t]);     // 256B contiguous store
  }
}

// ---------------- Kernel 7: per-sample conv as implicit GEMM -----------------
// (Round-1 proven version.) Block tile: M=128 (co) x N=128 (2 rows x 64 cols).
// K-loop: 9 taps x 4 ci-chunks of 32 (BK=32), 16x16x32 bf16 MFMA.
// x staged per ci-half (64 ci) in LDS NHWC with 16B XOR swizzle; A double-buffered.
#define XTILE_B 33792   // 264 positions * 128B (64 ci bf16)
#define ATILE_B 8192    // 128 co * 64B (32 ci bf16)

__global__ __launch_bounds__(256) void dyn_conv_kernel(
    const __hip_bfloat16* __restrict__ xT, const __hip_bfloat16* __restrict__ aggw,
    const float* __restrict__ aggb, float* __restrict__ out) {
  const int tile = blockIdx.x;   // 0..31 -> rows [2*tile, 2*tile+1]
  const int b    = blockIdx.y;   // sample
  const int tid  = threadIdx.x;
  const int wv = tid >> 6, lane = tid & 63;
  const int wm = wv >> 1, wn = wv & 1;
  const int lm = lane & 15, quad = lane >> 4;
  const int r0 = tile * 2;

  __shared__ __align__(16) char smem[XTILE_B + 2 * ATILE_B + 512];
  char* xb = smem;
  char* abuf = smem + XTILE_B;
  float* sBias = (float*)(smem + XTILE_B + 2 * ATILE_B);

  if (tid < 128) sBias[tid] = aggb[b * 128 + tid];

  // zero-fill halo slots that staging never writes (pad cols / out-of-range rows)
  for (int pos = tid; pos < 264; pos += 256) {
    int tr = pos / 66, tc = pos - tr * 66;
    int h = r0 - 1 + tr, w = tc - 1;
    if ((unsigned)h >= 64u || (unsigned)w >= 64u) {
      int4* d = (int4*)(xb + pos * 128);
      #pragma unroll
      for (int i = 0; i < 8; ++i) d[i] = make_int4(0, 0, 0, 0);
    }
  }

  const char* xTb = (const char*)xT + ((size_t)b << 20);     // b*4096*256
  const char* awb = (const char*)aggw + (size_t)b * 294912;  // b*9*128*256

  auto stageX = [&](int half) {
    for (int i = wv; i < 33; i += 4) {          // 33 issues of 64x16B = 1KB
      int P = (i << 6) + lane;
      int pos = P >> 3, slot = P & 7;
      int tr = pos / 66, tc = pos - tr * 66;
      int h = r0 - 1 + tr, w = tc - 1;
      char* dst = xb + (i << 10);               // wave-uniform LDS base
      if ((unsigned)h < 64u && (unsigned)w < 64u) {
        int p = slot ^ (pos & 7);               // swizzled source piece
        const char* src = xTb + (((h << 6) + w) << 8) + (half << 7) + (p << 4);
        g2l16(src, dst);
      }
    }
  };
  auto stageA = [&](int c) {                    // chunk c -> buffer c&1
    int tap = (c % 18) >> 1;
    int cic = ((c / 18) << 1) | (c & 1);        // ci chunk 0..3
    char* ab = abuf + (c & 1) * ATILE_B;
    const char* base = awb + (tap << 15);
    #pragma unroll
    for (int jj = 0; jj < 2; ++jj) {
      int j = wv * 2 + jj;
      int co = (j << 4) + (lane >> 2);
      int f = lane & 3;
      int p = f ^ ((co >> 1) & 3);              // swizzled source piece
      const char* src = base + (co << 8) + (cic << 6) + (p << 4);
      g2l16(src, ab + (j << 10));
    }
  };

  int posb[4];
  #pragma unroll
  for (int ni = 0; ni < 4; ++ni) {
    int n = wn * 64 + ni * 16 + lm;
    posb[ni] = (n >> 6) * 66 + (n & 63);
  }
  const int fA = (quad ^ ((lm >> 1) & 3)) << 4;
  int aoff[4];
  #pragma unroll
  for (int mi = 0; mi < 4; ++mi) {
    int co = wm * 64 + mi * 16 + lm;
    aoff[mi] = (co << 6) + fA;
  }

  v4f acc[4][4];
  #pragma unroll
  for (int mi = 0; mi < 4; ++mi)
    #pragma unroll
    for (int ni = 0; ni < 4; ++ni) acc[mi][ni] = v4f{0.f, 0.f, 0.f, 0.f};

  auto computeChunk = [&](int c) {
    int tap = (c % 18) >> 1, sub = c & 1;
    int th = tap / 3, tw = tap - th * 3;
    char* ab = abuf + (c & 1) * ATILE_B;
    v8bf af[4], bfr[4];
    #pragma unroll
    for (int mi = 0; mi < 4; ++mi) af[mi] = *(const v8bf*)(ab + aoff[mi]);
    const int piece = (sub << 2) | quad;        // ci piece within half
    #pragma unroll
    for (int ni = 0; ni < 4; ++ni) {
      int pos = posb[ni] + th * 66 + tw;
      int pp = (piece ^ (pos & 7)) << 4;
      bfr[ni] = *(const v8bf*)(xb + (pos << 7) + pp);
    }
    #pragma unroll
    for (int mi = 0; mi < 4; ++mi)
      #pragma unroll
      for (int ni = 0; ni < 4; ++ni)
        acc[mi][ni] = __builtin_amdgcn_mfma_f32_16x16x32_bf16(
            af[mi], bfr[ni], acc[mi][ni], 0, 0, 0);
  };

  // ---- main loop: x half 0 (chunks 0..17), then half 1 (18..35) ----
  stageX(0);
  stageA(0);
  __syncthreads();
  for (int c = 0; c < 18; ++c) {
    if (c < 17) stageA(c + 1);
    computeChunk(c);
    __syncthreads();
  }
  stageX(1);
  stageA(18);
  __syncthreads();
  for (int c = 18; c < 36; ++c) {
    if (c < 35) stageA(c + 1);
    computeChunk(c);
    __syncthreads();
  }

  // ---- epilogue: C/D layout col=lane&15, row=quad*4+reg ----
  #pragma unroll
  for (int mi = 0; mi < 4; ++mi) {
    #pragma unroll
    for (int r = 0; r < 4; ++r) {
      int co = wm * 64 + mi * 16 + quad * 4 + r;
      float bias = sBias[co];
      #pragma unroll
      for (int ni = 0; ni < 4; ++ni) {
        int n = wn * 64 + ni * 16 + lm;
        out[(((size_t)(b * 128 + co)) << 12) + tile * 128 + n] =
            acc[mi][ni][r] + bias;
      }
    }
  }
}

// ---------------------------------- launch -----------------------------------
extern "C" void kernel_launch(void* const* d_in, const int* in_sizes, int n_in,
                              void* d_out, int out_size, void* d_ws, size_t ws_size,
                              hipStream_t stream) {
  const float* x      = (const float*)d_in[0];
  const float* prompt = (const float*)d_in[1];
  const float* w1     = (const float*)d_in[2];
  const float* b1     = (const float*)d_in[3];
  const float* w2     = (const float*)d_in[4];
  const float* b2     = (const float*)d_in[5];
  const float* kw     = (const float*)d_in[6];
  const float* kb     = (const float*)d_in[7];
  float* out = (float*)d_out;
  char* ws = (char*)d_ws;

  __hip_bfloat16* xT   = (__hip_bfloat16*)(ws + XT_OFF);
  __hip_bfloat16* aggw = (__hip_bfloat16*)(ws + AGGW_OFF);
  float* part   = (float*)(ws + PART_OFF);     // aliases AGGW (dead before agg)
  float* pooled = (float*)(ws + POOLED_OFF);   // "
  float* hbuf   = (float*)(ws + H_OFF);        // "
  float* pscore = (float*)(ws + PSCORE_OFF);   // "
  float* alphas = (float*)(ws + ALPHA_OFF);
  float* aggb   = (float*)(ws + AGGB_OFF);

  pool_convert_kernel<<<2048, 256, 0, stream>>>(x, part, xT);
  pool_reduce_kernel<<<32, 128, 0, stream>>>(part, pooled);
  attn_l1_kernel<<<64, 256, 0, stream>>>(pooled, w1, b1, hbuf);
  attn_l2s_kernel<<<128, 256, 0, stream>>>(hbuf, w2, b2, prompt, pscore);
  softmax_aggb_kernel<<<32, 256, 0, stream>>>(pscore, kb, alphas, aggb);
  agg_weights_kernel<<<dim3(128, 4), 128, 0, stream>>>(kw, alphas, aggw);
  dyn_conv_kernel<<<dim3(32, 32), 256, 0, stream>>>(xT, aggw, aggb, out);
}